// Round 2
// baseline (303.702 us; speedup 1.0000x reference)
//
#include <hip/hip_runtime.h>

#define NN 3072
#define FF 512
#define HH 8
#define DD 64
#define SLOPEV 0.2f

typedef __bf16  bf16x8 __attribute__((ext_vector_type(8)));
typedef short   s16x8  __attribute__((ext_vector_type(8)));
typedef float   f32x4  __attribute__((ext_vector_type(4)));

#define MFMA16(a,b,c) __builtin_amdgcn_mfma_f32_16x16x32_bf16((a),(b),(c),0,0,0)

__device__ __forceinline__ short f2bf(float x){ __bf16 b=(__bf16)x; return __builtin_bit_cast(short,b); }
__device__ __forceinline__ float bf2f(short s){ return (float)__builtin_bit_cast(__bf16,s); }
__device__ __forceinline__ bf16x8 ldbf8(const short* p){ return __builtin_bit_cast(bf16x8, *(const s16x8*)p); }

// ---- K0a: split h (fp32) into bf16 hi/lo ----
__global__ __launch_bounds__(256) void k_split_h(const float* __restrict__ h,
    short* __restrict__ hhi, short* __restrict__ hlo){
  size_t base = ((size_t)blockIdx.x*256 + threadIdx.x)*8;
  float4 v0 = *(const float4*)(h+base);
  float4 v1 = *(const float4*)(h+base+4);
  float vv[8] = {v0.x,v0.y,v0.z,v0.w,v1.x,v1.y,v1.z,v1.w};
  s16x8 hi, lo;
  #pragma unroll
  for (int j=0;j<8;j++){ short s=f2bf(vv[j]); hi[j]=s; lo[j]=f2bf(vv[j]-bf2f(s)); }
  *(s16x8*)(hhi+base)=hi; *(s16x8*)(hlo+base)=lo;
}

// ---- K0b: W[h][f][d] -> WT[h][d][f] bf16 hi/lo, plus wa = W @ a (fp32) ----
__global__ __launch_bounds__(64) void k_wt(const float* __restrict__ W, const float* __restrict__ a,
    short* __restrict__ wthi, short* __restrict__ wtlo,
    float* __restrict__ wasrc, float* __restrict__ wadst){
  int h = blockIdx.y, f0 = blockIdx.x*8, d = threadIdx.x;   // 64 threads = 1 wave
  float asv = a[h*2*DD + d];
  float adv = a[h*2*DD + DD + d];
  s16x8 vh, vl;
  #pragma unroll
  for (int j=0;j<8;j++){
    float v = W[((size_t)h*FF + f0 + j)*DD + d];
    short s = f2bf(v); vh[j]=s; vl[j]=f2bf(v-bf2f(s));
    float ws_ = v*asv, wd_ = v*adv;
    #pragma unroll
    for (int m=1;m<64;m<<=1){ ws_ += __shfl_xor(ws_,m,64); wd_ += __shfl_xor(wd_,m,64); }
    if (d==0){ wasrc[h*FF+f0+j]=ws_; wadst[h*FF+f0+j]=wd_; }
  }
  size_t o = ((size_t)h*DD + d)*FF + f0;
  *(s16x8*)(wthi+o)=vh; *(s16x8*)(wtlo+o)=vl;
}

// ---- K1: src/dst = h @ wa  (fully fp32 -> exact softmax logits) ----
__global__ __launch_bounds__(256) void k_srcdst(const float* __restrict__ h,
    const float* __restrict__ wasrc, const float* __restrict__ wadst,
    float* __restrict__ src, float* __restrict__ dst){
  int wid = blockIdx.x*4 + (threadIdx.x>>6);      // one wave per (h,n)
  int lane = threadIdx.x & 63;
  int hh = wid / NN, n = wid - hh*NN;
  const float* hp = h + (size_t)n*FF + lane*8;
  const float* sp = wasrc + (size_t)hh*FF + lane*8;
  const float* dp = wadst + (size_t)hh*FF + lane*8;
  float4 x0 = *(const float4*)hp, x1 = *(const float4*)(hp+4);
  float4 s0 = *(const float4*)sp, s1 = *(const float4*)(sp+4);
  float4 t0 = *(const float4*)dp, t1 = *(const float4*)(dp+4);
  float s = x0.x*s0.x + x0.y*s0.y + x0.z*s0.z + x0.w*s0.w
          + x1.x*s1.x + x1.y*s1.y + x1.z*s1.z + x1.w*s1.w;
  float t = x0.x*t0.x + x0.y*t0.y + x0.z*t0.z + x0.w*t0.w
          + x1.x*t1.x + x1.y*t1.y + x1.z*t1.z + x1.w*t1.w;
  #pragma unroll
  for (int m=1;m<64;m<<=1){ s += __shfl_xor(s,m,64); t += __shfl_xor(t,m,64); }
  if (lane==0){ src[hh*NN+n]=s; dst[hh*NN+n]=t; }
}

// ---- K2: ht = h @ W[h] via split-bf16 MFMA (near-fp32); store htT[h][d][n] bf16 hi/lo ----
__global__ __launch_bounds__(128) void k_ht(const short* __restrict__ hhi, const short* __restrict__ hlo,
    const short* __restrict__ wthi, const short* __restrict__ wtlo,
    short* __restrict__ hthi, short* __restrict__ htlo){
  int h = blockIdx.y, n0 = blockIdx.x*32;
  int w = threadIdx.x>>6, lane = threadIdx.x&63;
  int r15 = lane&15, g = lane>>4;
  int arow = n0 + w*16 + r15;
  f32x4 acc[4] = {{0.f,0.f,0.f,0.f},{0.f,0.f,0.f,0.f},{0.f,0.f,0.f,0.f},{0.f,0.f,0.f,0.f}};
  const short* ha = hhi + (size_t)arow*FF + g*8;
  const short* la = hlo + (size_t)arow*FF + g*8;
  for (int kk=0; kk<FF; kk+=32){
    bf16x8 ahi = ldbf8(ha+kk), alo = ldbf8(la+kk);
    #pragma unroll
    for (int c=0;c<4;c++){
      size_t bo = ((size_t)h*DD + c*16 + r15)*FF + g*8 + kk;
      bf16x8 bh = ldbf8(wthi + bo), bl = ldbf8(wtlo + bo);
      acc[c] = MFMA16(ahi,bh,acc[c]);
      acc[c] = MFMA16(ahi,bl,acc[c]);
      acc[c] = MFMA16(alo,bh,acc[c]);
    }
  }
  #pragma unroll
  for (int c=0;c<4;c++){
    #pragma unroll
    for (int r=0;r<4;r++){
      float v = acc[c][r];                        // ht[n=n0+16w+4g+r][d=c*16+r15]
      short s = f2bf(v); short sl = f2bf(v - bf2f(s));
      int n = n0 + w*16 + g*4 + r;
      size_t o = ((size_t)h*DD + c*16 + r15)*NN + n;
      hthi[o]=s; htlo[o]=sl;
    }
  }
}

// ---- K3: fused masked-softmax + att write + hp (hp^T = htT * att^T via MFMA) ----
__global__ __launch_bounds__(128) void k_att(const int* __restrict__ adj,
    const float* __restrict__ src, const float* __restrict__ dst,
    const short* __restrict__ hthi, const short* __restrict__ htlo,
    float* __restrict__ dout){
  __shared__ float red[2][16];
  __shared__ float hpT[64][17];
  const size_t OUTOFF = (size_t)NN*HH*DD;
  int h = blockIdx.y, n0 = blockIdx.x*16;
  int w = threadIdx.x>>6, lane = threadIdx.x&63;
  int r15 = lane&15, g = lane>>4;
  int nrow = n0 + r15;
  float srcv = src[h*NN + nrow];
  const int* adjrow = adj + (size_t)nrow*NN;
  const float* dsth = dst + h*NN;
  int mbase = w*(NN/2);                            // wave w owns half the m-range

  // ---- sweep A: row sums of p = exp(leaky(src+dst)) masked ----
  float psum = 0.f;
  for (int t=0;t<48;t++){
    int mg = mbase + t*32 + g*8;
    int4 a0 = *(const int4*)(adjrow+mg); int4 a1 = *(const int4*)(adjrow+mg+4);
    float4 d0 = *(const float4*)(dsth+mg); float4 d1 = *(const float4*)(dsth+mg+4);
    int aj[8] = {a0.x,a0.y,a0.z,a0.w,a1.x,a1.y,a1.z,a1.w};
    float dj[8] = {d0.x,d0.y,d0.z,d0.w,d1.x,d1.y,d1.z,d1.w};
    #pragma unroll
    for (int j=0;j<8;j++){
      float e = srcv + dj[j];
      e = (e > 0.f) ? e : SLOPEV*e;
      float p = (aj[j] > 0) ? __expf(e) : 0.f;
      psum += p;
    }
  }
  psum += __shfl_xor(psum,16,64); psum += __shfl_xor(psum,32,64);
  if (lane < 16) red[w][lane] = psum;
  __syncthreads();
  float tot = red[0][r15] + red[1][r15];
  float inv = (tot > 0.f) ? 1.f/tot : (1.f/(float)NN);
  bool am = !(tot > 0.f);                          // all-masked row -> uniform 1/N

  // ---- sweep B: recompute p, write att, MFMA-accumulate hp^T ----
  f32x4 acc[4] = {{0.f,0.f,0.f,0.f},{0.f,0.f,0.f,0.f},{0.f,0.f,0.f,0.f},{0.f,0.f,0.f,0.f}};
  float* attrow = dout + OUTOFF + ((size_t)(h*NN + nrow))*NN;
  for (int t=0;t<48;t++){
    int mg = mbase + t*32 + g*8;
    int4 a0 = *(const int4*)(adjrow+mg); int4 a1 = *(const int4*)(adjrow+mg+4);
    float4 d0 = *(const float4*)(dsth+mg); float4 d1 = *(const float4*)(dsth+mg+4);
    int aj[8] = {a0.x,a0.y,a0.z,a0.w,a1.x,a1.y,a1.z,a1.w};
    float dj[8] = {d0.x,d0.y,d0.z,d0.w,d1.x,d1.y,d1.z,d1.w};
    float o[8];
    #pragma unroll
    for (int j=0;j<8;j++){
      float e = srcv + dj[j];
      e = (e > 0.f) ? e : SLOPEV*e;
      float p = (aj[j] > 0) ? __expf(e) : 0.f;
      if (am) p = 1.f;
      o[j] = p * inv;
    }
    f32x4 s0 = {o[0],o[1],o[2],o[3]};
    f32x4 s1 = {o[4],o[5],o[6],o[7]};
    __builtin_nontemporal_store(s0, (f32x4*)(attrow+mg));
    __builtin_nontemporal_store(s1, (f32x4*)(attrow+mg+4));
    bf16x8 bfrag;                                   // att^T B-fragment: col=r15 (n), k=8g+e (m)
    #pragma unroll
    for (int j=0;j<8;j++) bfrag[j] = (__bf16)o[j];
    #pragma unroll
    for (int c=0;c<4;c++){
      size_t ao = ((size_t)h*DD + c*16 + r15)*NN + mg;   // htT A-fragment: row=r15 (d), k contiguous m
      bf16x8 ahi = ldbf8(hthi + ao);
      bf16x8 alo = ldbf8(htlo + ao);
      acc[c] = MFMA16(ahi,bfrag,acc[c]);
      acc[c] = MFMA16(alo,bfrag,acc[c]);
    }
  }

  // ---- combine wave halves, write out[n][h*64+d] ----
  if (w==0){
    #pragma unroll
    for (int c=0;c<4;c++){
      #pragma unroll
      for (int r=0;r<4;r++) hpT[c*16 + g*4 + r][r15] = acc[c][r];
    }
  }
  __syncthreads();
  if (w==1){
    #pragma unroll
    for (int c=0;c<4;c++){
      #pragma unroll
      for (int r=0;r<4;r++) hpT[c*16 + g*4 + r][r15] += acc[c][r];
    }
  }
  __syncthreads();
  int n = threadIdx.x>>3, dd0 = (threadIdx.x&7)*8;
  f32x4 o0, o1;
  o0[0]=hpT[dd0+0][n]; o0[1]=hpT[dd0+1][n]; o0[2]=hpT[dd0+2][n]; o0[3]=hpT[dd0+3][n];
  o1[0]=hpT[dd0+4][n]; o1[1]=hpT[dd0+5][n]; o1[2]=hpT[dd0+6][n]; o1[3]=hpT[dd0+7][n];
  size_t ob = (size_t)(n0+n)*(HH*DD) + h*DD + dd0;
  __builtin_nontemporal_store(o0, (f32x4*)(dout+ob));
  __builtin_nontemporal_store(o1, (f32x4*)(dout+ob+4));
}

extern "C" void kernel_launch(void* const* d_in, const int* in_sizes, int n_in,
                              void* d_out, int out_size, void* d_ws, size_t ws_size,
                              hipStream_t stream) {
  const float* h   = (const float*)d_in[0];
  const int*   adj = (const int*)d_in[1];
  const float* W   = (const float*)d_in[2];
  const float* a   = (const float*)d_in[3];
  float* out = (float*)d_out;

  // workspace carve (~13.9 MB)
  short* hhi  = (short*)d_ws;
  short* hlo  = hhi  + (size_t)NN*FF;
  short* wthi = hlo  + (size_t)NN*FF;
  short* wtlo = wthi + (size_t)HH*DD*FF;
  short* hthi = wtlo + (size_t)HH*DD*FF;
  short* htlo = hthi + (size_t)HH*DD*NN;
  float* wasrc= (float*)(htlo + (size_t)HH*DD*NN);
  float* wadst= wasrc + HH*FF;
  float* srcb = wadst + HH*FF;
  float* dstb = srcb + HH*NN;

  k_split_h<<<dim3(NN*FF/(256*8)), 256, 0, stream>>>(h, hhi, hlo);
  k_wt     <<<dim3(FF/8, HH), 64, 0, stream>>>(W, a, wthi, wtlo, wasrc, wadst);
  k_srcdst <<<dim3(HH*NN/4), 256, 0, stream>>>(h, wasrc, wadst, srcb, dstb);
  k_ht     <<<dim3(NN/32, HH), 128, 0, stream>>>(hhi, hlo, wthi, wtlo, hthi, htlo);
  k_att    <<<dim3(NN/16, HH), 128, 0, stream>>>(adj, srcb, dstb, hthi, htlo, out);
}

// Round 3
// 284.730 us; speedup vs baseline: 1.0666x; 1.0666x over previous
//
#include <hip/hip_runtime.h>

#define NN 3072
#define FF 512
#define HH 8
#define DD 64
#define SLOPEV 0.2f

typedef __bf16  bf16x8 __attribute__((ext_vector_type(8)));
typedef short   s16x8  __attribute__((ext_vector_type(8)));
typedef float   f32x4  __attribute__((ext_vector_type(4)));

#define MFMA16(a,b,c) __builtin_amdgcn_mfma_f32_16x16x32_bf16((a),(b),(c),0,0,0)

__device__ __forceinline__ short f2bf(float x){ __bf16 b=(__bf16)x; return __builtin_bit_cast(short,b); }
__device__ __forceinline__ float bf2f(short s){ return (float)__builtin_bit_cast(__bf16,s); }
__device__ __forceinline__ bf16x8 ldbf8(const short* p){ return __builtin_bit_cast(bf16x8, *(const s16x8*)p); }

// ---- K0a: split h (fp32) into bf16 hi/lo ----
__global__ __launch_bounds__(256) void k_split_h(const float* __restrict__ h,
    short* __restrict__ hhi, short* __restrict__ hlo){
  size_t base = ((size_t)blockIdx.x*256 + threadIdx.x)*8;
  float4 v0 = *(const float4*)(h+base);
  float4 v1 = *(const float4*)(h+base+4);
  float vv[8] = {v0.x,v0.y,v0.z,v0.w,v1.x,v1.y,v1.z,v1.w};
  s16x8 hi, lo;
  #pragma unroll
  for (int j=0;j<8;j++){ short s=f2bf(vv[j]); hi[j]=s; lo[j]=f2bf(vv[j]-bf2f(s)); }
  *(s16x8*)(hhi+base)=hi; *(s16x8*)(hlo+base)=lo;
}

// ---- K0b: W[h][f][d] -> WT[h][d][f] bf16 hi/lo, plus wa = W @ a (fp32) ----
__global__ __launch_bounds__(64) void k_wt(const float* __restrict__ W, const float* __restrict__ a,
    short* __restrict__ wthi, short* __restrict__ wtlo,
    float* __restrict__ wasrc, float* __restrict__ wadst){
  int h = blockIdx.y, f0 = blockIdx.x*8, d = threadIdx.x;   // 64 threads = 1 wave
  float asv = a[h*2*DD + d];
  float adv = a[h*2*DD + DD + d];
  s16x8 vh, vl;
  #pragma unroll
  for (int j=0;j<8;j++){
    float v = W[((size_t)h*FF + f0 + j)*DD + d];
    short s = f2bf(v); vh[j]=s; vl[j]=f2bf(v-bf2f(s));
    float ws_ = v*asv, wd_ = v*adv;
    #pragma unroll
    for (int m=1;m<64;m<<=1){ ws_ += __shfl_xor(ws_,m,64); wd_ += __shfl_xor(wd_,m,64); }
    if (d==0){ wasrc[h*FF+f0+j]=ws_; wadst[h*FF+f0+j]=wd_; }
  }
  size_t o = ((size_t)h*DD + d)*FF + f0;
  *(s16x8*)(wthi+o)=vh; *(s16x8*)(wtlo+o)=vl;
}

// ---- K1: src/dst = h @ wa  (fully fp32 -> exact softmax logits) ----
__global__ __launch_bounds__(256) void k_srcdst(const float* __restrict__ h,
    const float* __restrict__ wasrc, const float* __restrict__ wadst,
    float* __restrict__ src, float* __restrict__ dst){
  int wid = blockIdx.x*4 + (threadIdx.x>>6);      // one wave per (h,n)
  int lane = threadIdx.x & 63;
  int hh = wid / NN, n = wid - hh*NN;
  const float* hp = h + (size_t)n*FF + lane*8;
  const float* sp = wasrc + (size_t)hh*FF + lane*8;
  const float* dp = wadst + (size_t)hh*FF + lane*8;
  float4 x0 = *(const float4*)hp, x1 = *(const float4*)(hp+4);
  float4 s0 = *(const float4*)sp, s1 = *(const float4*)(sp+4);
  float4 t0 = *(const float4*)dp, t1 = *(const float4*)(dp+4);
  float s = x0.x*s0.x + x0.y*s0.y + x0.z*s0.z + x0.w*s0.w
          + x1.x*s1.x + x1.y*s1.y + x1.z*s1.z + x1.w*s1.w;
  float t = x0.x*t0.x + x0.y*t0.y + x0.z*t0.z + x0.w*t0.w
          + x1.x*t1.x + x1.y*t1.y + x1.z*t1.z + x1.w*t1.w;
  #pragma unroll
  for (int m=1;m<64;m<<=1){ s += __shfl_xor(s,m,64); t += __shfl_xor(t,m,64); }
  if (lane==0){ src[hh*NN+n]=s; dst[hh*NN+n]=t; }
}

// ---- K2: ht = h @ W[h] via split-bf16 MFMA (near-fp32); store htT[h][d][n] bf16 hi/lo ----
__global__ __launch_bounds__(128) void k_ht(const short* __restrict__ hhi, const short* __restrict__ hlo,
    const short* __restrict__ wthi, const short* __restrict__ wtlo,
    short* __restrict__ hthi, short* __restrict__ htlo){
  int h = blockIdx.y, n0 = blockIdx.x*32;
  int w = threadIdx.x>>6, lane = threadIdx.x&63;
  int r15 = lane&15, g = lane>>4;
  int arow = n0 + w*16 + r15;
  f32x4 acc[4] = {{0.f,0.f,0.f,0.f},{0.f,0.f,0.f,0.f},{0.f,0.f,0.f,0.f},{0.f,0.f,0.f,0.f}};
  const short* ha = hhi + (size_t)arow*FF + g*8;
  const short* la = hlo + (size_t)arow*FF + g*8;
  for (int kk=0; kk<FF; kk+=32){
    bf16x8 ahi = ldbf8(ha+kk), alo = ldbf8(la+kk);
    #pragma unroll
    for (int c=0;c<4;c++){
      size_t bo = ((size_t)h*DD + c*16 + r15)*FF + g*8 + kk;
      bf16x8 bh = ldbf8(wthi + bo), bl = ldbf8(wtlo + bo);
      acc[c] = MFMA16(ahi,bh,acc[c]);
      acc[c] = MFMA16(ahi,bl,acc[c]);
      acc[c] = MFMA16(alo,bh,acc[c]);
    }
  }
  #pragma unroll
  for (int c=0;c<4;c++){
    #pragma unroll
    for (int r=0;r<4;r++){
      float v = acc[c][r];                        // ht[n=n0+16w+4g+r][d=c*16+r15]
      short s = f2bf(v); short sl = f2bf(v - bf2f(s));
      int n = n0 + w*16 + g*4 + r;
      size_t o = ((size_t)h*DD + c*16 + r15)*NN + n;
      hthi[o]=s; htlo[o]=sl;
    }
  }
}

// ---- K3: fused masked-softmax + att write + hp (hp^T = htT * att^T via MFMA) ----
// 4 waves/block, each owns a quarter of the m-range -> 24 waves/CU (vs 12 before).
#define NW 4
#define TT (NN/(NW*32))   // 24 iterations per sweep per wave
__global__ __launch_bounds__(256) void k_att(const int* __restrict__ adj,
    const float* __restrict__ src, const float* __restrict__ dst,
    const short* __restrict__ hthi, const short* __restrict__ htlo,
    float* __restrict__ dout){
  __shared__ float red[NW][16];
  __shared__ float hpT[NW][64][17];
  const size_t OUTOFF = (size_t)NN*HH*DD;
  int h = blockIdx.y, n0 = blockIdx.x*16;
  int w = threadIdx.x>>6, lane = threadIdx.x&63;
  int r15 = lane&15, g = lane>>4;
  int nrow = n0 + r15;
  float srcv = src[h*NN + nrow];
  const int* adjrow = adj + (size_t)nrow*NN;
  const float* dsth = dst + h*NN;
  int mbase = w*(NN/NW);                           // wave w owns a quarter of m

  // ---- sweep A: row sums of p = exp(leaky(src+dst)) masked ----
  float psum = 0.f;
  for (int t=0;t<TT;t++){
    int mg = mbase + t*32 + g*8;
    int4 a0 = *(const int4*)(adjrow+mg); int4 a1 = *(const int4*)(adjrow+mg+4);
    float4 d0 = *(const float4*)(dsth+mg); float4 d1 = *(const float4*)(dsth+mg+4);
    int aj[8] = {a0.x,a0.y,a0.z,a0.w,a1.x,a1.y,a1.z,a1.w};
    float dj[8] = {d0.x,d0.y,d0.z,d0.w,d1.x,d1.y,d1.z,d1.w};
    #pragma unroll
    for (int j=0;j<8;j++){
      float e = srcv + dj[j];
      e = fmaxf(e, SLOPEV*e);
      float p = (aj[j] > 0) ? __expf(e) : 0.f;
      psum += p;
    }
  }
  psum += __shfl_xor(psum,16,64); psum += __shfl_xor(psum,32,64);
  if (lane < 16) red[w][lane] = psum;
  __syncthreads();
  float tot = red[0][r15] + red[1][r15] + red[2][r15] + red[3][r15];
  float inv = (tot > 0.f) ? 1.f/tot : (1.f/(float)NN);
  bool am = !(tot > 0.f);                          // all-masked row -> uniform 1/N

  // ---- sweep B: recompute p, write att, MFMA-accumulate hp^T ----
  f32x4 acc[4] = {{0.f,0.f,0.f,0.f},{0.f,0.f,0.f,0.f},{0.f,0.f,0.f,0.f},{0.f,0.f,0.f,0.f}};
  float* attrow = dout + OUTOFF + ((size_t)(h*NN + nrow))*NN;
  for (int t=0;t<TT;t++){
    int mg = mbase + t*32 + g*8;
    int4 a0 = *(const int4*)(adjrow+mg); int4 a1 = *(const int4*)(adjrow+mg+4);
    float4 d0 = *(const float4*)(dsth+mg); float4 d1 = *(const float4*)(dsth+mg+4);
    int aj[8] = {a0.x,a0.y,a0.z,a0.w,a1.x,a1.y,a1.z,a1.w};
    float dj[8] = {d0.x,d0.y,d0.z,d0.w,d1.x,d1.y,d1.z,d1.w};
    float o[8];
    #pragma unroll
    for (int j=0;j<8;j++){
      float e = srcv + dj[j];
      e = fmaxf(e, SLOPEV*e);
      float p = (aj[j] > 0) ? __expf(e) : 0.f;
      if (am) p = 1.f;
      o[j] = p * inv;
    }
    f32x4 s0 = {o[0],o[1],o[2],o[3]};
    f32x4 s1 = {o[4],o[5],o[6],o[7]};
    __builtin_nontemporal_store(s0, (f32x4*)(attrow+mg));
    __builtin_nontemporal_store(s1, (f32x4*)(attrow+mg+4));
    bf16x8 bfrag;                                   // att^T B-fragment: col=r15 (n), k=8g+e (m)
    #pragma unroll
    for (int j=0;j<8;j++) bfrag[j] = (__bf16)o[j];
    #pragma unroll
    for (int c=0;c<4;c++){
      size_t ao = ((size_t)h*DD + c*16 + r15)*NN + mg;   // htT A-fragment: row=r15 (d), k contiguous m
      bf16x8 ahi = ldbf8(hthi + ao);
      bf16x8 alo = ldbf8(htlo + ao);
      acc[c] = MFMA16(ahi,bfrag,acc[c]);
      acc[c] = MFMA16(alo,bfrag,acc[c]);
    }
  }

  // ---- per-wave hpT slices, then combined write out[n][h*64+d] ----
  #pragma unroll
  for (int c=0;c<4;c++){
    #pragma unroll
    for (int r=0;r<4;r++) hpT[w][c*16 + g*4 + r][r15] = acc[c][r];
  }
  __syncthreads();
  int n = threadIdx.x>>4, dd0 = (threadIdx.x&15)*4;
  f32x4 o0;
  #pragma unroll
  for (int k=0;k<4;k++)
    o0[k] = hpT[0][dd0+k][n] + hpT[1][dd0+k][n] + hpT[2][dd0+k][n] + hpT[3][dd0+k][n];
  size_t ob = (size_t)(n0+n)*(HH*DD) + h*DD + dd0;
  __builtin_nontemporal_store(o0, (f32x4*)(dout+ob));
}

extern "C" void kernel_launch(void* const* d_in, const int* in_sizes, int n_in,
                              void* d_out, int out_size, void* d_ws, size_t ws_size,
                              hipStream_t stream) {
  const float* h   = (const float*)d_in[0];
  const int*   adj = (const int*)d_in[1];
  const float* W   = (const float*)d_in[2];
  const float* a   = (const float*)d_in[3];
  float* out = (float*)d_out;

  // workspace carve (~13.9 MB)
  short* hhi  = (short*)d_ws;
  short* hlo  = hhi  + (size_t)NN*FF;
  short* wthi = hlo  + (size_t)NN*FF;
  short* wtlo = wthi + (size_t)HH*DD*FF;
  short* hthi = wtlo + (size_t)HH*DD*FF;
  short* htlo = hthi + (size_t)HH*DD*NN;
  float* wasrc= (float*)(htlo + (size_t)HH*DD*NN);
  float* wadst= wasrc + HH*FF;
  float* srcb = wadst + HH*FF;
  float* dstb = srcb + HH*NN;

  k_split_h<<<dim3(NN*FF/(256*8)), 256, 0, stream>>>(h, hhi, hlo);
  k_wt     <<<dim3(FF/8, HH), 64, 0, stream>>>(W, a, wthi, wtlo, wasrc, wadst);
  k_srcdst <<<dim3(HH*NN/4), 256, 0, stream>>>(h, wasrc, wadst, srcb, dstb);
  k_ht     <<<dim3(NN/32, HH), 128, 0, stream>>>(hhi, hlo, wthi, wtlo, hthi, htlo);
  k_att    <<<dim3(NN/16, HH), 256, 0, stream>>>(adj, srcb, dstb, hthi, htlo, out);
}